// Round 1
// baseline (936.455 us; speedup 1.0000x reference)
//
#include <hip/hip_runtime.h>

// Problem constants
#define T_STEPS 28
#define IN_DIM  28
#define HID     64
#define NB      64   // batch elements per block (= lanes)
#define NW      16   // waves per block; wave w owns hidden units 4w..4w+3 (i,f,g,o rows)

// Workspace layout (floats):
//  Wp0: [92 k][16 wave][16 r]   k<28 -> W_ih0, k>=28 -> W_hh0   (row = 64*(r>>2) + 4w + (r&3))
//  Wp1: [128 k][16 wave][16 r]  k<64 -> W_ih1, k>=64 -> W_hh1
//  bias:[2 layer][16 wave][16 r] = b_ih + b_hh
#define WP0_OFF  0
#define WP1_OFF  (92 * 256)
#define BIAS_OFF (92 * 256 + 128 * 256)
#define WS_FLOATS (BIAS_OFF + 512)

__global__ void prep_kernel(const float* __restrict__ Wih0, const float* __restrict__ Whh0,
                            const float* __restrict__ bih0, const float* __restrict__ bhh0,
                            const float* __restrict__ Wih1, const float* __restrict__ Whh1,
                            const float* __restrict__ bih1, const float* __restrict__ bhh1,
                            float* __restrict__ ws) {
    int idx = blockIdx.x * blockDim.x + threadIdx.x;
    int stride = gridDim.x * blockDim.x;
    for (int i = idx; i < WS_FLOATS; i += stride) {
        float v;
        if (i < WP1_OFF) {
            int k = i >> 8, wr = i & 255, w = wr >> 4, r = wr & 15;
            int row = ((r >> 2) << 6) + (w << 2) + (r & 3);
            v = (k < IN_DIM) ? Wih0[row * IN_DIM + k] : Whh0[row * HID + (k - IN_DIM)];
        } else if (i < BIAS_OFF) {
            int j = i - WP1_OFF;
            int k = j >> 8, wr = j & 255, w = wr >> 4, r = wr & 15;
            int row = ((r >> 2) << 6) + (w << 2) + (r & 3);
            v = (k < HID) ? Wih1[row * HID + k] : Whh1[row * HID + (k - HID)];
        } else {
            int j = i - BIAS_OFF;
            int layer = j >> 8, wr = j & 255, w = wr >> 4, r = wr & 15;
            int row = ((r >> 2) << 6) + (w << 2) + (r & 3);
            v = (layer == 0) ? (bih0[row] + bhh0[row]) : (bih1[row] + bhh1[row]);
        }
        ws[i] = v;
    }
}

__device__ __forceinline__ float sigf(float x) { return 1.0f / (1.0f + __expf(-x)); }
__device__ __forceinline__ float tanh_fast(float x) { return 1.0f - 2.0f / (__expf(2.0f * x) + 1.0f); }

// block = (64 lanes = batch, 16 waves = gate groups); 1 block/CU, 4 waves/SIMD -> VGPR <= 128
__launch_bounds__(1024, 4)
__global__ void lstm_fused(const float* __restrict__ x,
                           const float* __restrict__ ws,
                           const float* __restrict__ Wlin,
                           const float* __restrict__ blin,
                           float* __restrict__ out) {
    __shared__ float h0buf[HID][NB];   // [hidden j][batch lane], 2-way bank alias (free)
    __shared__ float h1buf[HID][NB];

    const int lane = threadIdx.x;          // batch within block
    const int w    = threadIdx.y;          // wave id (wave-uniform since blockDim.x == 64)
    const int b    = blockIdx.x * NB + lane;

    const float* __restrict__ Wp0 = ws + WP0_OFF;
    const float* __restrict__ Wp1 = ws + WP1_OFF;

    #pragma unroll
    for (int q = 0; q < 4; ++q) { h0buf[4 * w + q][lane] = 0.0f; h1buf[4 * w + q][lane] = 0.0f; }

    float c0[4] = {0.f, 0.f, 0.f, 0.f};
    float c1[4] = {0.f, 0.f, 0.f, 0.f};

    __syncthreads();

    for (int t = 0; t < T_STEPS; ++t) {
        float acc[16];
        {   // layer-0 bias (wave-uniform -> s_load)
            int bb = __builtin_amdgcn_readfirstlane(w * 16);
            #pragma unroll
            for (int r = 0; r < 16; ++r) acc[r] = ws[BIAS_OFF + bb + r];
        }

        // ---- layer 0: x contribution (k = 0..27), x row is 112B contiguous ----
        {
            const float4* xp = (const float4*)(x + b * 784 + t * IN_DIM);
            #pragma unroll
            for (int q = 0; q < 7; ++q) {
                float4 xv4 = xp[q];
                float xs[4] = {xv4.x, xv4.y, xv4.z, xv4.w};
                #pragma unroll
                for (int kk = 0; kk < 4; ++kk) {
                    int k = q * 4 + kk;
                    int base = __builtin_amdgcn_readfirstlane((k * 16 + w) * 16);
                    const float* wk = Wp0 + base;
                    #pragma unroll
                    for (int r = 0; r < 16; ++r) acc[r] += wk[r] * xs[kk];
                }
            }
        }

        // ---- layer 0: recurrent contribution (k = 0..63 over h0) ----
        #pragma unroll 8
        for (int k = 0; k < HID; ++k) {
            int base = __builtin_amdgcn_readfirstlane(((k + IN_DIM) * 16 + w) * 16);
            const float* wk = Wp0 + base;
            float hv = h0buf[k][lane];
            #pragma unroll
            for (int r = 0; r < 16; ++r) acc[r] += wk[r] * hv;
        }

        __syncthreads();   // (A) all waves done reading h0buf(prev)

        #pragma unroll
        for (int q = 0; q < 4; ++q) {
            float ig = sigf(acc[0 + q]);
            float fg = sigf(acc[4 + q]);
            float gg = tanh_fast(acc[8 + q]);
            float og = sigf(acc[12 + q]);
            float cc = fg * c0[q] + ig * gg;
            c0[q] = cc;
            h0buf[4 * w + q][lane] = og * tanh_fast(cc);
        }

        __syncthreads();   // (B) h0buf(new) visible

        {   // layer-1 bias
            int bb = __builtin_amdgcn_readfirstlane(w * 16);
            #pragma unroll
            for (int r = 0; r < 16; ++r) acc[r] = ws[BIAS_OFF + 256 + bb + r];
        }

        // ---- layer 1: input contribution (h0, k = 0..63) ----
        #pragma unroll 8
        for (int k = 0; k < HID; ++k) {
            int base = __builtin_amdgcn_readfirstlane((k * 16 + w) * 16);
            const float* wk = Wp1 + base;
            float hv = h0buf[k][lane];
            #pragma unroll
            for (int r = 0; r < 16; ++r) acc[r] += wk[r] * hv;
        }
        // ---- layer 1: recurrent contribution (h1, k = 0..63) ----
        #pragma unroll 8
        for (int k = 0; k < HID; ++k) {
            int base = __builtin_amdgcn_readfirstlane(((k + HID) * 16 + w) * 16);
            const float* wk = Wp1 + base;
            float hv = h1buf[k][lane];
            #pragma unroll
            for (int r = 0; r < 16; ++r) acc[r] += wk[r] * hv;
        }

        __syncthreads();   // (C) all waves done reading h1buf(prev)

        #pragma unroll
        for (int q = 0; q < 4; ++q) {
            float ig = sigf(acc[0 + q]);
            float fg = sigf(acc[4 + q]);
            float gg = tanh_fast(acc[8 + q]);
            float og = sigf(acc[12 + q]);
            float cc = fg * c1[q] + ig * gg;
            c1[q] = cc;
            h1buf[4 * w + q][lane] = og * tanh_fast(cc);
        }

        __syncthreads();   // (D) h1buf(new) visible
    }

    // ---- final linear: wave o (< 10) computes out[b][o] ----
    if (w < 10) {
        int base = __builtin_amdgcn_readfirstlane(w * HID);
        float a = blin[w];
        #pragma unroll 8
        for (int j = 0; j < HID; ++j) a += Wlin[base + j] * h1buf[j][lane];
        out[b * 10 + w] = a;
    }
}

extern "C" void kernel_launch(void* const* d_in, const int* in_sizes, int n_in,
                              void* d_out, int out_size, void* d_ws, size_t ws_size,
                              hipStream_t stream) {
    const float* x    = (const float*)d_in[0];
    const float* Wih0 = (const float*)d_in[1];
    const float* Whh0 = (const float*)d_in[2];
    const float* bih0 = (const float*)d_in[3];
    const float* bhh0 = (const float*)d_in[4];
    const float* Wih1 = (const float*)d_in[5];
    const float* Whh1 = (const float*)d_in[6];
    const float* bih1 = (const float*)d_in[7];
    const float* bhh1 = (const float*)d_in[8];
    const float* Wlin = (const float*)d_in[9];
    const float* blin = (const float*)d_in[10];
    float* out = (float*)d_out;
    float* ws  = (float*)d_ws;

    prep_kernel<<<64, 256, 0, stream>>>(Wih0, Whh0, bih0, bhh0, Wih1, Whh1, bih1, bhh1, ws);
    lstm_fused<<<16384 / NB, dim3(NB, NW), 0, stream>>>(x, ws, Wlin, blin, out);
}

// Round 2
// 258.935 us; speedup vs baseline: 3.6166x; 3.6166x over previous
//
#include <hip/hip_runtime.h>

// ---------------- MFMA fp16 LSTM ----------------
// GEMM per step-layer:  C[m=gate(256)][n=batch(64)] = W[m][k] * data[k][n]
// Gate rows permuted: row' = 4*unit + gate  (gate: 0=i,1=f,2=g,3=o; orig row = gate*64 + unit)
// => C-tile lane layout (col=lane&15=batch, row=quad*4+r) puts i/f/g/o of one unit
//    in one lane's 4 C-registers. c-state stays in VGPRs across all 28 steps.
// A (weights) preloaded in registers once; bias0 folded in as k=28 constant-1 column.
// B (x/h data) in LDS "frag-linear" layout: one frag = 1KB, lane reads 16B at lane*16
//    (conflict-free ds_read_b128). B[k][n]: n=lane&15, k=quad*8+j.
// K layouts: layer0 K=96: k0..27=x, k28=1.0(bias), k29..31=0, k32..95=h0  (3 k-tiles)
//            layer1 K=128: k0..63=h0_new, k64..127=h1_prev                (4 k-tiles)

typedef _Float16 half8 __attribute__((ext_vector_type(8)));
typedef float floatx4 __attribute__((ext_vector_type(4)));

#define NFRAG 112                 // 16 mt * 3 kt (layer0) + 16 mt * 4 kt (layer1)
#define WS_BIAS_OFF (NFRAG * 1024)  // bytes into d_ws where fp32 bias1[256] lives

__global__ void prep_kernel(const float* __restrict__ Wih0, const float* __restrict__ Whh0,
                            const float* __restrict__ bih0, const float* __restrict__ bhh0,
                            const float* __restrict__ Wih1, const float* __restrict__ Whh1,
                            const float* __restrict__ bih1, const float* __restrict__ bhh1,
                            _Float16* __restrict__ wA, float* __restrict__ wBias) {
    int idx = blockIdx.x * blockDim.x + threadIdx.x;
    if (idx < NFRAG * 512) {
        int f = idx >> 9, slot = idx & 511;
        int lane = slot >> 3, j = slot & 7;
        int mt, kt, layer;
        if (f < 48) { layer = 0; mt = f / 3; kt = f % 3; }
        else        { layer = 1; int f2 = f - 48; mt = f2 >> 2; kt = f2 & 3; }
        int m = mt * 16 + (lane & 15);          // permuted gate-row
        int k = kt * 32 + (lane >> 4) * 8 + j;  // A[m][k]: m=lane&15, k=quad*8+j
        int u = m >> 2, g = m & 3;
        int row = g * 64 + u;                    // original weight row
        float v;
        if (layer == 0) {
            if (k < 28)       v = Wih0[row * 28 + k];
            else if (k == 28) v = bih0[row] + bhh0[row];   // bias0 via constant-1 input
            else if (k < 32)  v = 0.f;
            else              v = Whh0[row * 64 + (k - 32)];
        } else {
            if (k < 64)       v = Wih1[row * 64 + k];
            else              v = Whh1[row * 64 + (k - 64)];
        }
        wA[idx] = (_Float16)v;
    } else if (idx < NFRAG * 512 + 256) {
        int m = idx - NFRAG * 512;
        int row = (m & 3) * 64 + (m >> 2);
        wBias[m] = bih1[row] + bhh1[row];
    }
}

__device__ __forceinline__ float sigf(float v)   { return 1.0f / (1.0f + __expf(-v)); }
__device__ __forceinline__ float tanhf2(float v) { return 1.0f - 2.0f / (__expf(2.0f * v) + 1.0f); }

// block = (64, 16): 16 waves. Wave w: mtg=w>>1 (2 m-tiles), ntg=w&1 (2 n-tiles).
__launch_bounds__(1024, 4)
__global__ void lstm_mfma(const float* __restrict__ x,
                          const _Float16* __restrict__ wA,
                          const float* __restrict__ wBias,
                          const float* __restrict__ Wlin,
                          const float* __restrict__ blin,
                          float* __restrict__ out) {
    __shared__ __align__(16) _Float16 h0p[2][4096];  // [parity][(nt*2+kt)*512 + lane*8 + j]
    __shared__ __align__(16) _Float16 h1p[2][4096];
    __shared__ __align__(16) _Float16 xb[2][2048];   // [parity][nt*512 + lane*8 + j]
    __shared__ float wlin_s[640];
    __shared__ float blin_s[10];

    const int lane = threadIdx.x;
    const int w    = threadIdx.y;
    const int tid  = w * 64 + lane;
    const int mtg  = w >> 1;
    const int ntg  = w & 1;
    const int quad = lane >> 4;
    const int col  = lane & 15;

    // ---- preload A fragments (weights, constant across t) ----
    half8 A0[2][3], A1[2][4];
    #pragma unroll
    for (int im = 0; im < 2; ++im) {
        int mt = mtg * 2 + im;
        #pragma unroll
        for (int kt = 0; kt < 3; ++kt)
            A0[im][kt] = *(const half8*)(wA + (mt * 3 + kt) * 512 + lane * 8);
        #pragma unroll
        for (int kt = 0; kt < 4; ++kt)
            A1[im][kt] = *(const half8*)(wA + (48 + mt * 4 + kt) * 512 + lane * 8);
    }
    floatx4 bias1[2];
    #pragma unroll
    for (int im = 0; im < 2; ++im) {
        const float* bp = wBias + (mtg * 2 + im) * 16 + quad * 4;
        bias1[im][0] = bp[0]; bias1[im][1] = bp[1]; bias1[im][2] = bp[2]; bias1[im][3] = bp[3];
    }

    // ---- zero h planes (parity 0) and stage x(t=0) ----
    {
        int* z0 = (int*)&h0p[0][0];
        int* z1 = (int*)&h1p[0][0];
        #pragma unroll
        for (int i = tid; i < 2048; i += 1024) { z0[i] = 0; z1[i] = 0; }
    }
    {
        #pragma unroll
        for (int s = 0; s < 2; ++s) {
            int slot = tid + s * 1024;
            int b = slot >> 5, i = slot & 31;
            float xv = 0.f;
            if (i < 28) xv = x[(blockIdx.x * 64 + b) * 784 + i];
            _Float16 hv = (i == 28) ? (_Float16)1.0f : (_Float16)xv;
            xb[0][(b >> 4) * 512 + ((i >> 3) * 16 + (b & 15)) * 8 + (i & 7)] = hv;
        }
    }
    __syncthreads();

    float c0[4] = {0.f, 0.f, 0.f, 0.f};
    float c1[4] = {0.f, 0.f, 0.f, 0.f};

    for (int t = 0; t < 28; ++t) {
        const int p = t & 1;

        // prefetch x(t+1) from global (latency covered by S1+S2 compute)
        float xn[2] = {0.f, 0.f};
        if (t < 27) {
            #pragma unroll
            for (int s = 0; s < 2; ++s) {
                int slot = tid + s * 1024;
                int b = slot >> 5, i = slot & 31;
                if (i < 28) xn[s] = x[(blockIdx.x * 64 + b) * 784 + (t + 1) * 28 + i];
            }
        }

        // ======== layer 0 ========
        floatx4 acc[2][2];
        #pragma unroll
        for (int im = 0; im < 2; ++im)
            #pragma unroll
            for (int in = 0; in < 2; ++in)
                acc[im][in] = (floatx4){0.f, 0.f, 0.f, 0.f};

        #pragma unroll
        for (int in = 0; in < 2; ++in) {            // x part (kt=0, bias folded)
            int nt = ntg * 2 + in;
            half8 bf = *(const half8*)&xb[p][nt * 512 + lane * 8];
            #pragma unroll
            for (int im = 0; im < 2; ++im)
                acc[im][in] = __builtin_amdgcn_mfma_f32_16x16x32_f16(A0[im][0], bf, acc[im][in], 0, 0, 0);
        }
        #pragma unroll
        for (int kt = 0; kt < 2; ++kt) {            // h0_prev part
            #pragma unroll
            for (int in = 0; in < 2; ++in) {
                int nt = ntg * 2 + in;
                half8 bf = *(const half8*)&h0p[p][(nt * 2 + kt) * 512 + lane * 8];
                #pragma unroll
                for (int im = 0; im < 2; ++im)
                    acc[im][in] = __builtin_amdgcn_mfma_f32_16x16x32_f16(A0[im][kt + 1], bf, acc[im][in], 0, 0, 0);
            }
        }
        #pragma unroll
        for (int im = 0; im < 2; ++im) {            // gates -> c0, h0_new
            int u = (mtg * 2 + im) * 4 + quad;
            #pragma unroll
            for (int in = 0; in < 2; ++in) {
                int nt = ntg * 2 + in;
                floatx4 a = acc[im][in];
                float ig = sigf(a[0]), fg = sigf(a[1]), gg = tanhf2(a[2]), og = sigf(a[3]);
                float c = fg * c0[im * 2 + in] + ig * gg;
                c0[im * 2 + in] = c;
                float h = og * tanhf2(c);
                h0p[1 - p][(nt * 2 + (u >> 5)) * 512 + (((u >> 3) & 3) * 16 + col) * 8 + (u & 7)] = (_Float16)h;
            }
        }
        __syncthreads();   // h0_new visible

        // ======== layer 1 ========
        #pragma unroll
        for (int im = 0; im < 2; ++im)
            #pragma unroll
            for (int in = 0; in < 2; ++in)
                acc[im][in] = bias1[im];

        #pragma unroll
        for (int kt = 0; kt < 2; ++kt) {            // h0_new part
            #pragma unroll
            for (int in = 0; in < 2; ++in) {
                int nt = ntg * 2 + in;
                half8 bf = *(const half8*)&h0p[1 - p][(nt * 2 + kt) * 512 + lane * 8];
                #pragma unroll
                for (int im = 0; im < 2; ++im)
                    acc[im][in] = __builtin_amdgcn_mfma_f32_16x16x32_f16(A1[im][kt], bf, acc[im][in], 0, 0, 0);
            }
        }
        #pragma unroll
        for (int kt = 0; kt < 2; ++kt) {            // h1_prev part
            #pragma unroll
            for (int in = 0; in < 2; ++in) {
                int nt = ntg * 2 + in;
                half8 bf = *(const half8*)&h1p[p][(nt * 2 + kt) * 512 + lane * 8];
                #pragma unroll
                for (int im = 0; im < 2; ++im)
                    acc[im][in] = __builtin_amdgcn_mfma_f32_16x16x32_f16(A1[im][kt + 2], bf, acc[im][in], 0, 0, 0);
            }
        }
        #pragma unroll
        for (int im = 0; im < 2; ++im) {            // gates -> c1, h1_new
            int u = (mtg * 2 + im) * 4 + quad;
            #pragma unroll
            for (int in = 0; in < 2; ++in) {
                int nt = ntg * 2 + in;
                floatx4 a = acc[im][in];
                float ig = sigf(a[0]), fg = sigf(a[1]), gg = tanhf2(a[2]), og = sigf(a[3]);
                float c = fg * c1[im * 2 + in] + ig * gg;
                c1[im * 2 + in] = c;
                float h = og * tanhf2(c);
                h1p[1 - p][(nt * 2 + (u >> 5)) * 512 + (((u >> 3) & 3) * 16 + col) * 8 + (u & 7)] = (_Float16)h;
            }
        }
        // stage x(t+1) into xb[1-p]
        if (t < 27) {
            #pragma unroll
            for (int s = 0; s < 2; ++s) {
                int slot = tid + s * 1024;
                int b = slot >> 5, i = slot & 31;
                _Float16 hv = (i == 28) ? (_Float16)1.0f : (_Float16)xn[s];
                xb[1 - p][(b >> 4) * 512 + ((i >> 3) * 16 + (b & 15)) * 8 + (i & 7)] = hv;
            }
        }
        __syncthreads();   // h1_new + x(t+1) visible
    }

    // ---- epilogue: out = h1_last @ Wlin^T + blin ----
    // h1_last is in h1p[0] (t=27 wrote parity 1-(27&1) = 0), fp16 frag layout.
    if (tid < 640) wlin_s[tid] = Wlin[tid];
    if (tid < 10)  blin_s[tid] = blin[tid];
    __syncthreads();
    if (tid < 640) {
        int b = tid / 10, o = tid - b * 10;
        float a = blin_s[o];
        #pragma unroll 8
        for (int u = 0; u < 64; ++u) {
            float hv = (float)h1p[0][((b >> 4) * 2 + (u >> 5)) * 512 + (((u >> 3) & 3) * 16 + (b & 15)) * 8 + (u & 7)];
            a += wlin_s[o * 64 + u] * hv;
        }
        out[(blockIdx.x * 64 + b) * 10 + o] = a;
    }
}

extern "C" void kernel_launch(void* const* d_in, const int* in_sizes, int n_in,
                              void* d_out, int out_size, void* d_ws, size_t ws_size,
                              hipStream_t stream) {
    const float* x    = (const float*)d_in[0];
    const float* Wih0 = (const float*)d_in[1];
    const float* Whh0 = (const float*)d_in[2];
    const float* bih0 = (const float*)d_in[3];
    const float* bhh0 = (const float*)d_in[4];
    const float* Wih1 = (const float*)d_in[5];
    const float* Whh1 = (const float*)d_in[6];
    const float* bih1 = (const float*)d_in[7];
    const float* bhh1 = (const float*)d_in[8];
    const float* Wlin = (const float*)d_in[9];
    const float* blin = (const float*)d_in[10];
    float* out = (float*)d_out;

    _Float16* wA    = (_Float16*)d_ws;
    float*    wBias = (float*)((char*)d_ws + WS_BIAS_OFF);

    prep_kernel<<<225, 256, 0, stream>>>(Wih0, Whh0, bih0, bhh0, Wih1, Whh1, bih1, bhh1, wA, wBias);
    lstm_mfma<<<256, dim3(64, 16), 0, stream>>>(x, wA, wBias, Wlin, blin, out);
}

// Round 3
// 205.181 us; speedup vs baseline: 4.5641x; 1.2620x over previous
//
#include <hip/hip_runtime.h>

// ---------------- MFMA fp16 LSTM, single fused kernel ----------------
// GEMM per step-layer:  C[m=gate(256)][n=batch(64)] = W[m][k] * data[k][n]
// Gate rows permuted: row' = 4*unit + gate (gate: 0=i,1=f,2=g,3=o; orig row = gate*64+unit)
// => C-tile lane layout (col=lane&15=batch, row=quad*4+r) puts i/f/g/o of one unit in one
//    lane's 4 C-regs; c-state lives in VGPRs across all 28 steps.
// A (weights) gathered from global fp32 ONCE per block into 56 VGPRs (no prep kernel, no ws).
// bias0 folded as k=28 constant-1 column; bias1 pre-added into the accumulator init.
// B (x/h) in LDS frag-linear layout: lane reads 16B at lane*16 (conflict-free ds_read_b128).
// K: layer0 K=96 (x 0..27, bias 28, pad, h0 32..95); layer1 K=128 (h0_new, h1_prev).
// Activations: __expf + __builtin_amdgcn_rcpf (avoids IEEE div-fixup sequence, ~5 divs/unit).

typedef _Float16 half8 __attribute__((ext_vector_type(8)));
typedef float floatx4 __attribute__((ext_vector_type(4)));

__device__ __forceinline__ float sigf(float v) {
    return __builtin_amdgcn_rcpf(1.0f + __expf(-v));          // exp->inf => rcp->0, saturates clean
}
__device__ __forceinline__ float tanhf2(float v) {
    return 1.0f - 2.0f * __builtin_amdgcn_rcpf(__expf(2.0f * v) + 1.0f);
}

// block = (64, 16): wave w -> mtg=w>>1 (2 m-tiles), ntg=w&1 (2 n-tiles)
__launch_bounds__(1024, 4)
__global__ void lstm_mfma(const float* __restrict__ x,
                          const float* __restrict__ Wih0, const float* __restrict__ Whh0,
                          const float* __restrict__ bih0, const float* __restrict__ bhh0,
                          const float* __restrict__ Wih1, const float* __restrict__ Whh1,
                          const float* __restrict__ bih1, const float* __restrict__ bhh1,
                          const float* __restrict__ Wlin, const float* __restrict__ blin,
                          float* __restrict__ out) {
    __shared__ __align__(16) _Float16 h0p[2][4096];  // [parity][(nt*2+kt)*512 + lane*8 + j]
    __shared__ __align__(16) _Float16 h1p[2][4096];
    __shared__ __align__(16) _Float16 xb[2][2048];   // [parity][nt*512 + lane*8 + j]
    __shared__ float wlin_s[640];
    __shared__ float blin_s[10];

    const int lane = threadIdx.x;
    const int w    = threadIdx.y;
    const int tid  = w * 64 + lane;
    const int mtg  = w >> 1;
    const int ntg  = w & 1;
    const int quad = lane >> 4;
    const int col  = lane & 15;

    // ---- gather A fragments from global fp32 weights (one-time; L2-resident) ----
    // A[m][k] frag: m = lane&15 (= col), k = quad*8 + j
    half8 A0[2][3], A1[2][4];
    #pragma unroll
    for (int im = 0; im < 2; ++im) {
        int mt = mtg * 2 + im;
        int m  = mt * 16 + col;
        int u  = m >> 2, g = m & 3;
        int row = g * 64 + u;                       // original weight row
        #pragma unroll
        for (int kt = 0; kt < 3; ++kt) {
            half8 r;
            #pragma unroll
            for (int j = 0; j < 8; ++j) {
                int k = kt * 32 + quad * 8 + j;
                float v;
                if (k < 28)       v = Wih0[row * 28 + k];
                else if (k == 28) v = bih0[row] + bhh0[row];
                else if (k < 32)  v = 0.f;
                else              v = Whh0[row * 64 + (k - 32)];
                r[j] = (_Float16)v;
            }
            A0[im][kt] = r;
        }
        #pragma unroll
        for (int kt = 0; kt < 4; ++kt) {
            half8 r;
            #pragma unroll
            for (int j = 0; j < 8; ++j) {
                int k = kt * 32 + quad * 8 + j;
                float v = (k < 64) ? Wih1[row * 64 + k] : Whh1[row * 64 + (k - 64)];
                r[j] = (_Float16)v;
            }
            A1[im][kt] = r;
        }
    }
    floatx4 bias1[2];
    #pragma unroll
    for (int im = 0; im < 2; ++im) {
        int u = (mtg * 2 + im) * 4 + quad;
        #pragma unroll
        for (int r = 0; r < 4; ++r) bias1[im][r] = bih1[r * 64 + u] + bhh1[r * 64 + u];
    }

    // ---- t-invariant LDS offsets (in halves) ----
    int xrd[2], hrd[2][2], hwr[2][2];
    #pragma unroll
    for (int in = 0; in < 2; ++in) {
        int nt = ntg * 2 + in;
        xrd[in] = nt * 512 + lane * 8;
        #pragma unroll
        for (int kt = 0; kt < 2; ++kt) hrd[kt][in] = (nt * 2 + kt) * 512 + lane * 8;
        #pragma unroll
        for (int im = 0; im < 2; ++im) {
            int u = (mtg * 2 + im) * 4 + quad;
            hwr[im][in] = (nt * 2 + (u >> 5)) * 512 + (((u >> 3) & 3) * 16 + col) * 8 + (u & 7);
        }
    }

    // ---- x prefetch pointers (slot s handles b=(tid>>5)+32s, i=tid&31) ----
    const int xi = tid & 31;
    const bool xvalid = xi < 28;
    const float* xg[2];
    int xstg[2];
    #pragma unroll
    for (int s = 0; s < 2; ++s) {
        int b = (tid >> 5) + s * 32;
        xg[s]   = x + (blockIdx.x * 64 + b) * 784 + xi;
        xstg[s] = (b >> 4) * 512 + ((xi >> 3) * 16 + (b & 15)) * 8 + (xi & 7);
    }

    // ---- zero h planes (parity 0), stage x(t=0) ----
    {
        int* z0 = (int*)&h0p[0][0];
        int* z1 = (int*)&h1p[0][0];
        #pragma unroll
        for (int i = tid; i < 2048; i += 1024) { z0[i] = 0; z1[i] = 0; }
        #pragma unroll
        for (int s = 0; s < 2; ++s) {
            float xv = xvalid ? xg[s][0] : 0.f;
            xb[0][xstg[s]] = (xi == 28) ? (_Float16)1.0f : (_Float16)xv;
        }
    }
    __syncthreads();

    float c0[4] = {0.f, 0.f, 0.f, 0.f};
    float c1[4] = {0.f, 0.f, 0.f, 0.f};

    for (int t = 0; t < 28; ++t) {
        const int p = t & 1, q = p ^ 1;
        _Float16* h0r = h0p[p];
        _Float16* h0w = h0p[q];
        _Float16* h1r = h1p[p];
        _Float16* h1w = h1p[q];
        const _Float16* xr = xb[p];

        // prefetch x(t+1) (latency hidden under layer0+layer1 compute)
        float xn[2] = {0.f, 0.f};
        if (t < 27) {
            #pragma unroll
            for (int s = 0; s < 2; ++s)
                if (xvalid) xn[s] = xg[s][(t + 1) * 28];
        }

        // ======== layer 0 ========
        floatx4 acc[2][2];
        #pragma unroll
        for (int im = 0; im < 2; ++im)
            #pragma unroll
            for (int in = 0; in < 2; ++in)
                acc[im][in] = (floatx4){0.f, 0.f, 0.f, 0.f};

        #pragma unroll
        for (int in = 0; in < 2; ++in) {            // x part (kt=0, bias folded)
            half8 bf = *(const half8*)&xr[xrd[in]];
            #pragma unroll
            for (int im = 0; im < 2; ++im)
                acc[im][in] = __builtin_amdgcn_mfma_f32_16x16x32_f16(A0[im][0], bf, acc[im][in], 0, 0, 0);
        }
        #pragma unroll
        for (int kt = 0; kt < 2; ++kt) {            // h0_prev
            #pragma unroll
            for (int in = 0; in < 2; ++in) {
                half8 bf = *(const half8*)&h0r[hrd[kt][in]];
                #pragma unroll
                for (int im = 0; im < 2; ++im)
                    acc[im][in] = __builtin_amdgcn_mfma_f32_16x16x32_f16(A0[im][kt + 1], bf, acc[im][in], 0, 0, 0);
            }
        }
        #pragma unroll
        for (int im = 0; im < 2; ++im) {            // gates -> c0, h0_new
            #pragma unroll
            for (int in = 0; in < 2; ++in) {
                floatx4 a = acc[im][in];
                float ig = sigf(a[0]), fg = sigf(a[1]), gg = tanhf2(a[2]), og = sigf(a[3]);
                float c = fg * c0[im * 2 + in] + ig * gg;
                c0[im * 2 + in] = c;
                h0w[hwr[im][in]] = (_Float16)(og * tanhf2(c));
            }
        }
        __syncthreads();   // h0_new visible

        // ======== layer 1 ========
        #pragma unroll
        for (int im = 0; im < 2; ++im)
            #pragma unroll
            for (int in = 0; in < 2; ++in)
                acc[im][in] = bias1[im];

        #pragma unroll
        for (int kt = 0; kt < 2; ++kt) {            // h0_new
            #pragma unroll
            for (int in = 0; in < 2; ++in) {
                half8 bf = *(const half8*)&h0w[hrd[kt][in]];
                #pragma unroll
                for (int im = 0; im < 2; ++im)
                    acc[im][in] = __builtin_amdgcn_mfma_f32_16x16x32_f16(A1[im][kt], bf, acc[im][in], 0, 0, 0);
            }
        }
        #pragma unroll
        for (int kt = 0; kt < 2; ++kt) {            // h1_prev
            #pragma unroll
            for (int in = 0; in < 2; ++in) {
                half8 bf = *(const half8*)&h1r[hrd[kt][in]];
                #pragma unroll
                for (int im = 0; im < 2; ++im)
                    acc[im][in] = __builtin_amdgcn_mfma_f32_16x16x32_f16(A1[im][kt + 2], bf, acc[im][in], 0, 0, 0);
            }
        }
        #pragma unroll
        for (int im = 0; im < 2; ++im) {            // gates -> c1, h1_new
            #pragma unroll
            for (int in = 0; in < 2; ++in) {
                floatx4 a = acc[im][in];
                float ig = sigf(a[0]), fg = sigf(a[1]), gg = tanhf2(a[2]), og = sigf(a[3]);
                float c = fg * c1[im * 2 + in] + ig * gg;
                c1[im * 2 + in] = c;
                h1w[hwr[im][in]] = (_Float16)(og * tanhf2(c));
            }
        }
        // stage x(t+1)
        if (t < 27) {
            #pragma unroll
            for (int s = 0; s < 2; ++s)
                xb[q][xstg[s]] = (xi == 28) ? (_Float16)1.0f : (_Float16)xn[s];
        }
        __syncthreads();   // h1_new + x(t+1) visible
    }

    // ---- epilogue: out = h1_last @ Wlin^T + blin  (h1_last in h1p[0]) ----
    if (tid < 640) wlin_s[tid] = Wlin[tid];
    if (tid < 10)  blin_s[tid] = blin[tid];
    __syncthreads();
    if (tid < 640) {
        int b = tid / 10, o = tid - b * 10;
        float a = blin_s[o];
        #pragma unroll 8
        for (int u = 0; u < 64; ++u) {
            float hv = (float)h1p[0][((b >> 4) * 2 + (u >> 5)) * 512 + (((u >> 3) & 3) * 16 + (b & 15)) * 8 + (u & 7)];
            a += wlin_s[o * 64 + u] * hv;
        }
        out[(blockIdx.x * 64 + b) * 10 + o] = a;
    }
}

extern "C" void kernel_launch(void* const* d_in, const int* in_sizes, int n_in,
                              void* d_out, int out_size, void* d_ws, size_t ws_size,
                              hipStream_t stream) {
    const float* x    = (const float*)d_in[0];
    const float* Wih0 = (const float*)d_in[1];
    const float* Whh0 = (const float*)d_in[2];
    const float* bih0 = (const float*)d_in[3];
    const float* bhh0 = (const float*)d_in[4];
    const float* Wih1 = (const float*)d_in[5];
    const float* Whh1 = (const float*)d_in[6];
    const float* bih1 = (const float*)d_in[7];
    const float* bhh1 = (const float*)d_in[8];
    const float* Wlin = (const float*)d_in[9];
    const float* blin = (const float*)d_in[10];
    float* out = (float*)d_out;

    lstm_mfma<<<256, dim3(64, 16), 0, stream>>>(x, Wih0, Whh0, bih0, bhh0,
                                                Wih1, Whh1, bih1, bhh1, Wlin, blin, out);
}

// Round 4
// 202.019 us; speedup vs baseline: 4.6355x; 1.0156x over previous
//
#include <hip/hip_runtime.h>

// ---------------- MFMA fp16 LSTM, single fused kernel, 2 blocks/CU ----------------
// Block = 512 thr (8 waves) over 32 batch columns; grid = 512 -> 2 independent
// barrier domains per CU (fills s_barrier stalls that capped the 1024-thr version).
// GEMM per step-layer: C[m=gate(256)][n=batch(32)] = W[m][k] * data[k][n]
// Gate rows permuted row'=4*unit+gate => lane's 4 C-regs = i,f,g,o of one unit;
// c-state lives in VGPRs across all 28 steps.
// Wave w owns m-tiles {2w, 2w+1} x n-tiles {0,1} (4 C-tiles).
// A (weights) gathered from global fp32 once per block into regs (L2-resident).
// bias0 folded as k=28 constant-1 column; bias1 pre-added into acc init.
// B (x/h) in LDS frag-linear layout: lane reads 16B at lane*16 (conflict-free b128).
// K: layer0 K=96 (x 0..27, bias 28, pad, h0 32..95); layer1 K=128 (h0_new, h1_prev).
// layer1's h1_prev MFMAs hoisted BEFORE barrier A (inputs ready since prev barrier).

typedef _Float16 half8 __attribute__((ext_vector_type(8)));
typedef float floatx4 __attribute__((ext_vector_type(4)));

__device__ __forceinline__ float sigf(float v) {
    return __builtin_amdgcn_rcpf(1.0f + __expf(-v));
}
__device__ __forceinline__ float tanhf2(float v) {
    return 1.0f - 2.0f * __builtin_amdgcn_rcpf(__expf(2.0f * v) + 1.0f);
}

__launch_bounds__(512, 4)
__global__ void lstm_mfma(const float* __restrict__ x,
                          const float* __restrict__ Wih0, const float* __restrict__ Whh0,
                          const float* __restrict__ bih0, const float* __restrict__ bhh0,
                          const float* __restrict__ Wih1, const float* __restrict__ Whh1,
                          const float* __restrict__ bih1, const float* __restrict__ bhh1,
                          const float* __restrict__ Wlin, const float* __restrict__ blin,
                          float* __restrict__ out) {
    __shared__ __align__(16) _Float16 h0p[2][2048];  // [parity][(nt*2+kt)*512 + lane*8 + j]
    __shared__ __align__(16) _Float16 h1p[2][2048];
    __shared__ __align__(16) _Float16 xb[2][1024];   // [parity][nt*512 + lane*8 + j]
    __shared__ float wlin_s[640];
    __shared__ float blin_s[10];

    const int lane = threadIdx.x;
    const int w    = threadIdx.y;          // 0..7
    const int tid  = w * 64 + lane;        // 0..511
    const int quad = lane >> 4;
    const int col  = lane & 15;

    // ---- gather A fragments from global fp32 weights (one-time; L2-resident) ----
    // A[m][k] frag: m = lane&15, k = quad*8 + j
    half8 A0[2][3], A1[2][4];
    #pragma unroll
    for (int im = 0; im < 2; ++im) {
        int mt = 2 * w + im;
        int m  = mt * 16 + col;
        int u  = m >> 2, g = m & 3;
        int row = g * 64 + u;                       // original weight row
        #pragma unroll
        for (int kt = 0; kt < 3; ++kt) {
            half8 r;
            #pragma unroll
            for (int j = 0; j < 8; ++j) {
                int k = kt * 32 + quad * 8 + j;
                float v;
                if (k < 28)       v = Wih0[row * 28 + k];
                else if (k == 28) v = bih0[row] + bhh0[row];
                else if (k < 32)  v = 0.f;
                else              v = Whh0[row * 64 + (k - 32)];
                r[j] = (_Float16)v;
            }
            A0[im][kt] = r;
        }
        #pragma unroll
        for (int kt = 0; kt < 4; ++kt) {
            half8 r;
            #pragma unroll
            for (int j = 0; j < 8; ++j) {
                int k = kt * 32 + quad * 8 + j;
                float v = (k < 64) ? Wih1[row * 64 + k] : Whh1[row * 64 + (k - 64)];
                r[j] = (_Float16)v;
            }
            A1[im][kt] = r;
        }
    }
    floatx4 bias1[2];
    #pragma unroll
    for (int im = 0; im < 2; ++im) {
        int u = (2 * w + im) * 4 + quad;
        #pragma unroll
        for (int r = 0; r < 4; ++r) bias1[im][r] = bih1[r * 64 + u] + bhh1[r * 64 + u];
    }

    // ---- t-invariant LDS offsets (halves) ----
    int xrd[2], hrd[2][2], hwr[2][2];
    #pragma unroll
    for (int in = 0; in < 2; ++in) {
        xrd[in] = in * 512 + lane * 8;
        #pragma unroll
        for (int kt = 0; kt < 2; ++kt) hrd[kt][in] = (in * 2 + kt) * 512 + lane * 8;
        #pragma unroll
        for (int im = 0; im < 2; ++im) {
            int u = (2 * w + im) * 4 + quad;
            hwr[im][in] = (in * 2 + (u >> 5)) * 512 + (((u >> 3) & 3) * 16 + col) * 8 + (u & 7);
        }
    }

    // ---- x prefetch: slot s covers b=(tid>>5)+16s, i=tid&31 (32 b x 32 i slots) ----
    const int xi = tid & 31;
    const bool xvalid = xi < 28;
    const float* xg[2];
    int xstg[2];
    #pragma unroll
    for (int s = 0; s < 2; ++s) {
        int b = (tid >> 5) + s * 16;
        xg[s]   = x + (blockIdx.x * 32 + b) * 784 + xi;
        xstg[s] = (b >> 4) * 512 + ((xi >> 3) * 16 + (b & 15)) * 8 + (xi & 7);
    }

    // ---- zero h planes (parity 0), stage x(t=0) ----
    {
        int* z0 = (int*)&h0p[0][0];
        int* z1 = (int*)&h1p[0][0];
        #pragma unroll
        for (int i = tid; i < 1024; i += 512) { z0[i] = 0; z1[i] = 0; }
        #pragma unroll
        for (int s = 0; s < 2; ++s) {
            float xv = xvalid ? xg[s][0] : 0.f;
            xb[0][xstg[s]] = (xi == 28) ? (_Float16)1.0f : (_Float16)xv;
        }
    }
    __syncthreads();

    float c0[4] = {0.f, 0.f, 0.f, 0.f};
    float c1[4] = {0.f, 0.f, 0.f, 0.f};

    for (int t = 0; t < 28; ++t) {
        const int p = t & 1, q = p ^ 1;
        _Float16* h0r = h0p[p];
        _Float16* h0w = h0p[q];
        _Float16* h1r = h1p[p];
        _Float16* h1w = h1p[q];
        const _Float16* xr = xb[p];

        // prefetch x(t+1) (latency hidden under step compute)
        float xn[2] = {0.f, 0.f};
        if (t < 27) {
            #pragma unroll
            for (int s = 0; s < 2; ++s)
                if (xvalid) xn[s] = xg[s][(t + 1) * 28];
        }

        // ---- layer0 MFMAs -> acc0 ----
        floatx4 acc0[2][2], acc1[2][2];
        #pragma unroll
        for (int im = 0; im < 2; ++im)
            #pragma unroll
            for (int in = 0; in < 2; ++in)
                acc0[im][in] = (floatx4){0.f, 0.f, 0.f, 0.f};

        #pragma unroll
        for (int in = 0; in < 2; ++in) {            // x part (kt=0, bias folded)
            half8 bf = *(const half8*)&xr[xrd[in]];
            #pragma unroll
            for (int im = 0; im < 2; ++im)
                acc0[im][in] = __builtin_amdgcn_mfma_f32_16x16x32_f16(A0[im][0], bf, acc0[im][in], 0, 0, 0);
        }
        #pragma unroll
        for (int kt = 0; kt < 2; ++kt) {            // h0_prev
            #pragma unroll
            for (int in = 0; in < 2; ++in) {
                half8 bf = *(const half8*)&h0r[hrd[kt][in]];
                #pragma unroll
                for (int im = 0; im < 2; ++im)
                    acc0[im][in] = __builtin_amdgcn_mfma_f32_16x16x32_f16(A0[im][kt + 1], bf, acc0[im][in], 0, 0, 0);
            }
        }

        // ---- layer1 h1_prev part -> acc1 (pre-barrier: inputs ready since prev step) ----
        #pragma unroll
        for (int im = 0; im < 2; ++im)
            #pragma unroll
            for (int in = 0; in < 2; ++in)
                acc1[im][in] = bias1[im];
        #pragma unroll
        for (int kt = 0; kt < 2; ++kt) {
            #pragma unroll
            for (int in = 0; in < 2; ++in) {
                half8 bf = *(const half8*)&h1r[hrd[kt][in]];
                #pragma unroll
                for (int im = 0; im < 2; ++im)
                    acc1[im][in] = __builtin_amdgcn_mfma_f32_16x16x32_f16(A1[im][kt + 2], bf, acc1[im][in], 0, 0, 0);
            }
        }

        // ---- layer0 gates -> c0, h0_new ----
        #pragma unroll
        for (int im = 0; im < 2; ++im) {
            #pragma unroll
            for (int in = 0; in < 2; ++in) {
                floatx4 a = acc0[im][in];
                float ig = sigf(a[0]), fg = sigf(a[1]), gg = tanhf2(a[2]), og = sigf(a[3]);
                float c = fg * c0[im * 2 + in] + ig * gg;
                c0[im * 2 + in] = c;
                h0w[hwr[im][in]] = (_Float16)(og * tanhf2(c));
            }
        }
        __syncthreads();   // (A) h0_new visible

        // ---- layer1 h0_new part -> acc1 ----
        #pragma unroll
        for (int kt = 0; kt < 2; ++kt) {
            #pragma unroll
            for (int in = 0; in < 2; ++in) {
                half8 bf = *(const half8*)&h0w[hrd[kt][in]];
                #pragma unroll
                for (int im = 0; im < 2; ++im)
                    acc1[im][in] = __builtin_amdgcn_mfma_f32_16x16x32_f16(A1[im][kt], bf, acc1[im][in], 0, 0, 0);
            }
        }

        // ---- layer1 gates -> c1, h1_new ----
        #pragma unroll
        for (int im = 0; im < 2; ++im) {
            #pragma unroll
            for (int in = 0; in < 2; ++in) {
                floatx4 a = acc1[im][in];
                float ig = sigf(a[0]), fg = sigf(a[1]), gg = tanhf2(a[2]), og = sigf(a[3]);
                float c = fg * c1[im * 2 + in] + ig * gg;
                c1[im * 2 + in] = c;
                h1w[hwr[im][in]] = (_Float16)(og * tanhf2(c));
            }
        }
        // stage x(t+1)
        if (t < 27) {
            #pragma unroll
            for (int s = 0; s < 2; ++s)
                xb[q][xstg[s]] = (xi == 28) ? (_Float16)1.0f : (_Float16)xn[s];
        }
        __syncthreads();   // (B) h1_new + x(t+1) visible
    }

    // ---- epilogue: out = h1_last @ Wlin^T + blin  (h1_last in h1p[0]) ----
    #pragma unroll
    for (int i = tid; i < 640; i += 512) wlin_s[i] = Wlin[i];
    if (tid < 10) blin_s[tid] = blin[tid];
    __syncthreads();
    if (tid < 320) {
        int b = tid / 10, o = tid - b * 10;
        float a = blin_s[o];
        #pragma unroll 8
        for (int u = 0; u < 64; ++u) {
            float hv = (float)h1p[0][((b >> 4) * 2 + (u >> 5)) * 512 + (((u >> 3) & 3) * 16 + (b & 15)) * 8 + (u & 7)];
            a += wlin_s[o * 64 + u] * hv;
        }
        out[(blockIdx.x * 32 + b) * 10 + o] = a;
    }
}

extern "C" void kernel_launch(void* const* d_in, const int* in_sizes, int n_in,
                              void* d_out, int out_size, void* d_ws, size_t ws_size,
                              hipStream_t stream) {
    const float* x    = (const float*)d_in[0];
    const float* Wih0 = (const float*)d_in[1];
    const float* Whh0 = (const float*)d_in[2];
    const float* bih0 = (const float*)d_in[3];
    const float* bhh0 = (const float*)d_in[4];
    const float* Wih1 = (const float*)d_in[5];
    const float* Whh1 = (const float*)d_in[6];
    const float* bih1 = (const float*)d_in[7];
    const float* bhh1 = (const float*)d_in[8];
    const float* Wlin = (const float*)d_in[9];
    const float* blin = (const float*)d_in[10];
    float* out = (float*)d_out;

    lstm_mfma<<<512, dim3(64, 8), 0, stream>>>(x, Wih0, Whh0, bih0, bhh0,
                                               Wih1, Whh1, bih1, bhh1, Wlin, blin, out);
}

// Round 5
// 197.864 us; speedup vs baseline: 4.7328x; 1.0210x over previous
//
#include <hip/hip_runtime.h>

// ------- MFMA fp16 LSTM, skewed-layer pipeline: ONE barrier per step -------
// Phase p (p=-1..27) computes layer1(t=p) AND layer0(t=p+1) between barriers:
//   layer1(p)  reads h0(p), h1(p-1)   -> writes h1(p)
//   layer0(p+1) reads x(p+1), h0(p)   -> writes h0(p+1)
// Both GEMMs share the h0(p) B-fragments (one ds_read, two uses).
// 29 barriers total vs 56 in the 2-barrier-per-step structure; each phase has
// two independent GEMM+gate chains to fill MFMA/LDS/transcendental latency.
//
// GEMM: C[m=gate(256)][n=batch(32)] = W[m][k] * data[k][n], gate rows permuted
// row'=4*unit+gate so a lane's 4 C-regs = (i,f,g,o) of one unit; c-state in VGPRs.
// Block = 512 thr (8 waves), wave w owns m-tiles {2w,2w+1} x n-tiles {0,1}.
// A (weights) gathered once per block from global fp32 (L2-resident).
// bias0 folded as k=28 constant-1 column; bias1 pre-added into acc init.
// B in LDS frag-linear layout: lane reads 16B at lane*16, conflict-free b128.
// Planes: h0(t) in h0p[t&1], h1(t) in h1p[t&1], x(t) in xb[t&1].

typedef _Float16 half8 __attribute__((ext_vector_type(8)));
typedef float floatx4 __attribute__((ext_vector_type(4)));

__device__ __forceinline__ float sigf(float v) {
    return __builtin_amdgcn_rcpf(1.0f + __expf(-v));
}
__device__ __forceinline__ float tanhf2(float v) {
    return 1.0f - 2.0f * __builtin_amdgcn_rcpf(__expf(2.0f * v) + 1.0f);
}

__launch_bounds__(512, 4)
__global__ void lstm_mfma(const float* __restrict__ x,
                          const float* __restrict__ Wih0, const float* __restrict__ Whh0,
                          const float* __restrict__ bih0, const float* __restrict__ bhh0,
                          const float* __restrict__ Wih1, const float* __restrict__ Whh1,
                          const float* __restrict__ bih1, const float* __restrict__ bhh1,
                          const float* __restrict__ Wlin, const float* __restrict__ blin,
                          float* __restrict__ out) {
    __shared__ __align__(16) _Float16 h0p[2][2048];  // [parity][(nt*2+kt)*512 + lane*8 + j]
    __shared__ __align__(16) _Float16 h1p[2][2048];
    __shared__ __align__(16) _Float16 xb[2][1024];   // [parity][nt*512 + lane*8 + j]
    __shared__ float wlin_s[640];
    __shared__ float blin_s[10];

    const int lane = threadIdx.x;
    const int w    = threadIdx.y;          // 0..7
    const int tid  = w * 64 + lane;        // 0..511
    const int quad = lane >> 4;
    const int col  = lane & 15;

    // ---- gather A fragments from global fp32 weights (one-time; L2-resident) ----
    half8 A0[2][3], A1[2][4];
    #pragma unroll
    for (int im = 0; im < 2; ++im) {
        int mt = 2 * w + im;
        int m  = mt * 16 + col;
        int u  = m >> 2, g = m & 3;
        int row = g * 64 + u;                       // original weight row
        #pragma unroll
        for (int kt = 0; kt < 3; ++kt) {
            half8 r;
            #pragma unroll
            for (int j = 0; j < 8; ++j) {
                int k = kt * 32 + quad * 8 + j;
                float v;
                if (k < 28)       v = Wih0[row * 28 + k];
                else if (k == 28) v = bih0[row] + bhh0[row];
                else if (k < 32)  v = 0.f;
                else              v = Whh0[row * 64 + (k - 32)];
                r[j] = (_Float16)v;
            }
            A0[im][kt] = r;
        }
        #pragma unroll
        for (int kt = 0; kt < 4; ++kt) {
            half8 r;
            #pragma unroll
            for (int j = 0; j < 8; ++j) {
                int k = kt * 32 + quad * 8 + j;
                float v = (k < 64) ? Wih1[row * 64 + k] : Whh1[row * 64 + (k - 64)];
                r[j] = (_Float16)v;
            }
            A1[im][kt] = r;
        }
    }
    floatx4 bias1[2];
    #pragma unroll
    for (int im = 0; im < 2; ++im) {
        int u = (2 * w + im) * 4 + quad;
        #pragma unroll
        for (int r = 0; r < 4; ++r) bias1[im][r] = bih1[r * 64 + u] + bhh1[r * 64 + u];
    }

    // ---- t-invariant LDS offsets (halves) ----
    int xrd[2], hrd[2][2], hwr[2][2];
    #pragma unroll
    for (int in = 0; in < 2; ++in) {
        xrd[in] = in * 512 + lane * 8;
        #pragma unroll
        for (int kt = 0; kt < 2; ++kt) hrd[kt][in] = (in * 2 + kt) * 512 + lane * 8;
        #pragma unroll
        for (int im = 0; im < 2; ++im) {
            int u = (2 * w + im) * 4 + quad;
            hwr[im][in] = (in * 2 + (u >> 5)) * 512 + (((u >> 3) & 3) * 16 + col) * 8 + (u & 7);
        }
    }

    // ---- x prefetch: slot s covers b=(tid>>5)+16s, i=tid&31 ----
    const int xi = tid & 31;
    const bool xvalid = xi < 28;
    const float* xg[2];
    int xstg[2];
    #pragma unroll
    for (int s = 0; s < 2; ++s) {
        int b = (tid >> 5) + s * 16;
        xg[s]   = x + (blockIdx.x * 32 + b) * 784 + xi;
        xstg[s] = (b >> 4) * 512 + ((xi >> 3) * 16 + (b & 15)) * 8 + (xi & 7);
    }

    // ---- init: zero h0(-1)=h0p[1], h1(-1)=h1p[1]; stage x(0) into xb[0] ----
    {
        int* z0 = (int*)&h0p[1][0];
        int* z1 = (int*)&h1p[1][0];
        #pragma unroll
        for (int i = tid; i < 1024; i += 512) { z0[i] = 0; z1[i] = 0; }
        #pragma unroll
        for (int s = 0; s < 2; ++s) {
            float xv = xvalid ? xg[s][0] : 0.f;
            xb[0][xstg[s]] = (xi == 28) ? (_Float16)1.0f : (_Float16)xv;
        }
    }
    __syncthreads();

    float c0[4] = {0.f, 0.f, 0.f, 0.f};
    float c1[4] = {0.f, 0.f, 0.f, 0.f};

    for (int p = -1; p <= 27; ++p) {
        const int pr  = p & 1;          // h0(p) read plane; h1(p) write plane; x(p+2) stage plane
        const int pr1 = pr ^ 1;         // h0(p+1) write plane; x(p+1) & h1(p-1) read planes
        const bool doL0 = (p < 27);     // layer0(t=p+1)
        const bool doL1 = (p >= 0);     // layer1(t=p)

        // global prefetch x(p+2)
        float xn[2] = {0.f, 0.f};
        if (p <= 25) {
            #pragma unroll
            for (int s = 0; s < 2; ++s)
                if (xvalid) xn[s] = xg[s][(p + 2) * 28];
        }

        // ---- B-fragment loads (h0 shared by both GEMMs) ----
        half8 bh0[2][2];
        #pragma unroll
        for (int kt = 0; kt < 2; ++kt)
            #pragma unroll
            for (int in = 0; in < 2; ++in)
                bh0[kt][in] = *(const half8*)&h0p[pr][hrd[kt][in]];

        // ---- layer0(t=p+1): acc0 = W0 * [x(p+1); 1; h0(p)] ----
        if (doL0) {
            floatx4 acc0[2][2];
            #pragma unroll
            for (int im = 0; im < 2; ++im)
                #pragma unroll
                for (int in = 0; in < 2; ++in)
                    acc0[im][in] = (floatx4){0.f, 0.f, 0.f, 0.f};
            #pragma unroll
            for (int in = 0; in < 2; ++in) {
                half8 bf = *(const half8*)&xb[pr1][xrd[in]];
                #pragma unroll
                for (int im = 0; im < 2; ++im)
                    acc0[im][in] = __builtin_amdgcn_mfma_f32_16x16x32_f16(A0[im][0], bf, acc0[im][in], 0, 0, 0);
            }
            #pragma unroll
            for (int kt = 0; kt < 2; ++kt)
                #pragma unroll
                for (int in = 0; in < 2; ++in)
                    #pragma unroll
                    for (int im = 0; im < 2; ++im)
                        acc0[im][in] = __builtin_amdgcn_mfma_f32_16x16x32_f16(A0[im][kt + 1], bh0[kt][in], acc0[im][in], 0, 0, 0);
            #pragma unroll
            for (int im = 0; im < 2; ++im) {
                #pragma unroll
                for (int in = 0; in < 2; ++in) {
                    floatx4 a = acc0[im][in];
                    float ig = sigf(a[0]), fg = sigf(a[1]), gg = tanhf2(a[2]), og = sigf(a[3]);
                    float c = fg * c0[im * 2 + in] + ig * gg;
                    c0[im * 2 + in] = c;
                    h0p[pr1][hwr[im][in]] = (_Float16)(og * tanhf2(c));
                }
            }
        }

        // ---- layer1(t=p): acc1 = W1 * [h0(p); h1(p-1)] + bias1 ----
        if (doL1) {
            floatx4 acc1[2][2];
            #pragma unroll
            for (int im = 0; im < 2; ++im)
                #pragma unroll
                for (int in = 0; in < 2; ++in)
                    acc1[im][in] = bias1[im];
            #pragma unroll
            for (int kt = 0; kt < 2; ++kt)
                #pragma unroll
                for (int in = 0; in < 2; ++in)
                    #pragma unroll
                    for (int im = 0; im < 2; ++im)
                        acc1[im][in] = __builtin_amdgcn_mfma_f32_16x16x32_f16(A1[im][kt], bh0[kt][in], acc1[im][in], 0, 0, 0);
            #pragma unroll
            for (int kt = 0; kt < 2; ++kt) {
                #pragma unroll
                for (int in = 0; in < 2; ++in) {
                    half8 bf = *(const half8*)&h1p[pr1][hrd[kt][in]];
                    #pragma unroll
                    for (int im = 0; im < 2; ++im)
                        acc1[im][in] = __builtin_amdgcn_mfma_f32_16x16x32_f16(A1[im][kt + 2], bf, acc1[im][in], 0, 0, 0);
                }
            }
            #pragma unroll
            for (int im = 0; im < 2; ++im) {
                #pragma unroll
                for (int in = 0; in < 2; ++in) {
                    floatx4 a = acc1[im][in];
                    float ig = sigf(a[0]), fg = sigf(a[1]), gg = tanhf2(a[2]), og = sigf(a[3]);
                    float c = fg * c1[im * 2 + in] + ig * gg;
                    c1[im * 2 + in] = c;
                    h1p[pr][hwr[im][in]] = (_Float16)(og * tanhf2(c));
                }
            }
        }

        // stage x(p+2) into xb[pr]
        if (p <= 25) {
            #pragma unroll
            for (int s = 0; s < 2; ++s)
                xb[pr][xstg[s]] = (xi == 28) ? (_Float16)1.0f : (_Float16)xn[s];
        }
        __syncthreads();   // h0(p+1), h1(p), x(p+2) visible
    }

    // ---- epilogue: out = h1(27) @ Wlin^T + blin   (h1(27) in h1p[1]) ----
    #pragma unroll
    for (int i = tid; i < 640; i += 512) wlin_s[i] = Wlin[i];
    if (tid < 10) blin_s[tid] = blin[tid];
    __syncthreads();
    if (tid < 320) {
        int b = tid / 10, o = tid - b * 10;
        float a = blin_s[o];
        #pragma unroll 8
        for (int u = 0; u < 64; ++u) {
            float hv = (float)h1p[1][((b >> 4) * 2 + (u >> 5)) * 512 + (((u >> 3) & 3) * 16 + (b & 15)) * 8 + (u & 7)];
            a += wlin_s[o * 64 + u] * hv;
        }
        out[(blockIdx.x * 32 + b) * 10 + o] = a;
    }
}

extern "C" void kernel_launch(void* const* d_in, const int* in_sizes, int n_in,
                              void* d_out, int out_size, void* d_ws, size_t ws_size,
                              hipStream_t stream) {
    const float* x    = (const float*)d_in[0];
    const float* Wih0 = (const float*)d_in[1];
    const float* Whh0 = (const float*)d_in[2];
    const float* bih0 = (const float*)d_in[3];
    const float* bhh0 = (const float*)d_in[4];
    const float* Wih1 = (const float*)d_in[5];
    const float* Whh1 = (const float*)d_in[6];
    const float* bih1 = (const float*)d_in[7];
    const float* bhh1 = (const float*)d_in[8];
    const float* Wlin = (const float*)d_in[9];
    const float* blin = (const float*)d_in[10];
    float* out = (float*)d_out;

    lstm_mfma<<<512, dim3(64, 8), 0, stream>>>(x, Wih0, Whh0, bih0, bhh0,
                                               Wih1, Whh1, bih1, bhh1, Wlin, blin, out);
}